// Round 8
// baseline (60.681 us; speedup 1.0000x reference)
//
#include <hip/hip_runtime.h>

#define B_SZ 256
#define D_SZ 256
#define M_SZ 65536
#define C_SZ 1000
#define TEMP 0.05f
#define EPSF 1e-6f

// ---- ws layout (bytes) ----
#define OFF_FCT   0          // float[D_SZ*C_SZ] = 1,024,000 B (transposed, pre-scaled)
#define OFF_NUMS  1024000    // int[C_SZ]
#define OFF_ACC   1028000    // float[2]
#define OFF_LCNT  1028008    // int[1] loss ticket

// One block per class. Each wave scans a disjoint quarter of labels (int4
// loads, L2-broadcast across blocks), ballot-matches lab==c, and for each
// match the whole wave gathers the 1KB feature row (lane = dims 4l..4l+3,
// float4) into register accumulators. No sort, no atomics, no scratch lists.
// Block 0 zeroes acc/lcnt for the following loss kernel.
__launch_bounds__(256)
__global__ void k_classscan(const float* __restrict__ features,
                            const int* __restrict__ labels,
                            float* __restrict__ fct, int* __restrict__ nums,
                            float* __restrict__ acc, int* __restrict__ lcnt) {
    int c = blockIdx.x;
    int t = threadIdx.x;
    int lane = t & 63, w = t >> 6;
    if (c == 0 && t == 0) { acc[0] = 0.f; acc[1] = 0.f; lcnt[0] = 0; }

    float4 a = make_float4(0.f, 0.f, 0.f, 0.f);
    int cnt = 0;
    const int wbase = w * (M_SZ / 4);            // 16384 labels per wave
    for (int i = 0; i < 64; ++i) {
        int base = wbase + i * 256;              // 256 labels per iteration
        int4 l4 = *(const int4*)&labels[base + lane * 4];
        #pragma unroll
        for (int u = 0; u < 4; ++u) {
            int lab = (u == 0) ? l4.x : (u == 1) ? l4.y : (u == 2) ? l4.z : l4.w;
            unsigned long long mask = __ballot(lab == c);
            cnt += (int)__popcll(mask);
            while (mask) {                        // rare: ~0.26 matches/iter
                int b = __ffsll(mask) - 1;
                mask &= mask - 1;
                int m = base + b * 4 + u;         // uniform across wave
                float4 v = *(const float4*)&features[(size_t)m * D_SZ + lane * 4];
                a.x += v.x; a.y += v.y; a.z += v.z; a.w += v.w;
            }
        }
    }
    // reduce the 4 wave-private accumulators
    __shared__ float4 red[4][64];
    __shared__ int cred[4];
    red[w][lane] = a;
    if (lane == 0) cred[w] = cnt;
    __syncthreads();
    if (w == 0) {
        float4 s0 = red[0][lane], s1 = red[1][lane];
        float4 s2 = red[2][lane], s3 = red[3][lane];
        float sx = (s0.x + s1.x) + (s2.x + s3.x);
        float sy = (s0.y + s1.y) + (s2.y + s3.y);
        float sz = (s0.z + s1.z) + (s2.z + s3.z);
        float sw = (s0.w + s1.w) + (s2.w + s3.w);
        int n = cred[0] + cred[1] + cred[2] + cred[3];
        float scale = 1.0f / (TEMP * (float)(n > 0 ? n : 1));
        int d0 = lane * 4;
        fct[(size_t)(d0 + 0) * C_SZ + c] = sx * scale;
        fct[(size_t)(d0 + 1) * C_SZ + c] = sy * scale;
        fct[(size_t)(d0 + 2) * C_SZ + c] = sz * scale;
        fct[(size_t)(d0 + 3) * C_SZ + c] = sw * scale;
        if (lane == 0) nums[c] = n;
    }
}

// One block (1024 thr) per TWO batch rows (2r, 2r+1); thread t = class t.
// (R7's proven version, unchanged.)
__launch_bounds__(1024)
__global__ void k_loss(const float* __restrict__ feat,
                       const float* __restrict__ fct,
                       const int* __restrict__ nums,
                       const float* __restrict__ soft,
                       const int* __restrict__ indexes,
                       const int* __restrict__ labels,
                       const int* __restrict__ bil,
                       const int* __restrict__ cur_epoch,
                       float* __restrict__ acc, int* __restrict__ lcnt,
                       float* __restrict__ out) {
    __shared__ float xs0[D_SZ], xs1[D_SZ];
    __shared__ float wred[16], wred2[16];
    __shared__ float bc0, bc1;
    __shared__ int tgt0, tgt1, sr0, sr1;

    int t = threadIdx.x;
    int lane = t & 63, wid = t >> 6;
    int r0 = blockIdx.x * 2;

    if (t == 0) {
        tgt0 = labels[indexes[r0]];
        tgt1 = labels[indexes[r0 + 1]];
        sr0 = bil[r0];
        sr1 = bil[r0 + 1];
    }

    // ---- normalize rows 2r,2r+1 (contiguous 512 floats) ----
    float v = (t < 512) ? feat[(size_t)r0 * D_SZ + t] : 0.f;
    float s = v * v;
    #pragma unroll
    for (int o = 32; o; o >>= 1) s += __shfl_down(s, o);
    if (lane == 0) wred[wid] = s;  // waves 0-3 = row0, 4-7 = row1
    __syncthreads();
    if (t == 0) {
        bc0 = fmaxf(sqrtf(wred[0] + wred[1] + wred[2] + wred[3]), 1e-12f);
        bc1 = fmaxf(sqrtf(wred[4] + wred[5] + wred[6] + wred[7]), 1e-12f);
    }
    __syncthreads();
    if (t < 256) xs0[t] = v / bc0;
    else if (t < 512) xs1[t - 256] = v / bc1;
    __syncthreads();

    // ---- sim + exp for class t, both rows ----
    float a0 = 0.f, a1 = 0.f;
    if (t < C_SZ) {
        #pragma unroll 8
        for (int i = 0; i < D_SZ; ++i) {
            float f = fct[(size_t)i * C_SZ + t];  // coalesced across lanes
            a0 = fmaf(xs0[i], f, a0);
            a1 = fmaf(xs1[i], f, a1);
        }
    }
    float mk = (t < C_SZ && nums[t] > 0) ? 1.f : 0.f;
    float e0 = mk * __expf(a0);
    float e1 = mk * __expf(a1);

    // ---- denominators over classes (both rows at once) ----
    float s0 = e0, s1 = e1;
    #pragma unroll
    for (int o = 32; o; o >>= 1) {
        s0 += __shfl_down(s0, o);
        s1 += __shfl_down(s1, o);
    }
    if (lane == 0) { wred[wid] = s0; wred2[wid] = s1; }
    __syncthreads();
    if (t == 0) {
        float z0 = 0.f, z1 = 0.f;
        #pragma unroll
        for (int i = 0; i < 16; ++i) { z0 += wred[i]; z1 += wred2[i]; }
        bc0 = z0; bc1 = z1;
    }
    __syncthreads();
    float inv0 = 1.0f / (bc0 + EPSF);
    float inv1 = 1.0f / (bc1 + EPSF);

    // ---- loss partials ----
    float p1 = 0.f, p2 = 0.f;
    if (t < C_SZ) {
        float lp0 = __logf(e0 * inv0 + EPSF);
        float lp1 = __logf(e1 * inv1 + EPSF);
        p2 = -(soft[(size_t)sr0 * C_SZ + t] * lp0 + soft[(size_t)sr1 * C_SZ + t] * lp1);
        if (t == tgt0) p1 -= lp0;
        if (t == tgt1) p1 -= lp1;
    }
    #pragma unroll
    for (int o = 32; o; o >>= 1) {
        p1 += __shfl_down(p1, o);
        p2 += __shfl_down(p2, o);
    }
    __syncthreads();
    if (lane == 0) { wred[wid] = p1; wred2[wid] = p2; }
    __syncthreads();
    if (t == 0) {
        float z1 = 0.f, z2 = 0.f;
        #pragma unroll
        for (int i = 0; i < 16; ++i) { z1 += wred[i]; z2 += wred2[i]; }
        atomicAdd(&acc[0], z1);
        atomicAdd(&acc[1], z2);
        __threadfence();
        int done = atomicAdd(lcnt, 1);
        if (done == (int)gridDim.x - 1) {
            float l1 = atomicAdd(&acc[0], 0.f) / (float)B_SZ;
            float l2 = atomicAdd(&acc[1], 0.f) / (float)B_SZ;
            out[0] = (cur_epoch[0] == 0) ? l1 : 0.5f * (l1 + l2);
        }
    }
}

extern "C" void kernel_launch(void* const* d_in, const int* in_sizes, int n_in,
                              void* d_out, int out_size, void* d_ws, size_t ws_size,
                              hipStream_t stream) {
    const float* feat     = (const float*)d_in[0];
    const float* features = (const float*)d_in[1];
    const float* soft     = (const float*)d_in[2];
    const int* indexes    = (const int*)d_in[3];
    const int* labels     = (const int*)d_in[4];
    const int* bil        = (const int*)d_in[5];
    const int* cur_epoch  = (const int*)d_in[6];

    char* ws = (char*)d_ws;
    float* fct   = (float*)(ws + OFF_FCT);
    int* nums    = (int*)(ws + OFF_NUMS);
    float* acc   = (float*)(ws + OFF_ACC);
    int* lcnt    = (int*)(ws + OFF_LCNT);

    k_classscan<<<C_SZ, 256, 0, stream>>>(features, labels, fct, nums, acc, lcnt);
    k_loss<<<B_SZ / 2, 1024, 0, stream>>>(feat, fct, nums, soft, indexes, labels,
                                          bil, cur_epoch, acc, lcnt, (float*)d_out);
}